// Round 10
// baseline (229.206 us; speedup 1.0000x reference)
//
#include <hip/hip_runtime.h>
#include <hip/hip_bf16.h>

// MultiBertAttention fp32 I/O, bf16 MFMA internals.
// R10: attn -> 32 q per wave (two B-operand sets), 256-thr blocks, 2 blocks/CU.
//      Each Ks b128 / Vs b64 fragment read now feeds TWO MFMAs -> per-q LDS
//      traffic halves (R9 model: LDS ~30us and exp ~27us were the co-bound
//      pipes; MFMA only ~7us). R9 lesson: SQ_LDS_BANK_CONFLICT is benign
//      multi-phase b128 accounting (identical 1.258e7 across different V
//      addressings) - stop optimizing it. GEMMs/prep unchanged from R9.

typedef unsigned short u16;

#define D_MODEL 1024
#define NHEAD 16
#define HDIM 64
#define BATCH 2
#define SEQ 2048
#define MTOT (BATCH * SEQ)  // 4096

#define QSCALE 0.18033688011112042f  // (1/8) * log2(e)

using frag_ab = __attribute__((ext_vector_type(8))) short;  // 8 bf16 (16x16x32 A/B)
using frag_s4 = __attribute__((ext_vector_type(4))) short;  // 4 bf16 (16x16x16 A/B)
using frag_cd = __attribute__((ext_vector_type(4))) float;  // 4 fp32

__device__ __forceinline__ u16 f2u(float f) {  // RNE fp32->bf16
    union { float f; unsigned int i; } x;
    x.f = f;
    unsigned int r = x.i + 0x7fffu + ((x.i >> 16) & 1u);
    return (u16)(r >> 16);
}
__device__ __forceinline__ unsigned int pkrn(float a, float b) {  // v_cvt_pk_bf16_f32
    union { __hip_bfloat162 h; unsigned int u; } c;
    c.h = __float22bfloat162_rn(float2{a, b});
    return c.u;
}

// ---------------------------------------------------------------------------
// prep: z<4 -> Wt[z][n][k] = bf16(W_z[k][n]); z==4 -> xb = bf16(x).
// ---------------------------------------------------------------------------
__global__ void prep(const float* __restrict__ W0, const float* __restrict__ W1,
                     const float* __restrict__ W2, const float* __restrict__ W3,
                     const float* __restrict__ X, u16* __restrict__ Wt,
                     u16* __restrict__ Xb) {
    const int z = blockIdx.z;
    const int tx = threadIdx.x, ty = threadIdx.y;
    if (z < 4) {
        __shared__ u16 t[32][33];
        const float* W = (z == 0) ? W0 : (z == 1) ? W1 : (z == 2) ? W2 : W3;
        u16* o = Wt + (size_t)z * D_MODEL * D_MODEL;
        int n0 = blockIdx.x * 32, k0 = blockIdx.y * 32;
        #pragma unroll
        for (int i = ty; i < 32; i += 8) t[i][tx] = f2u(W[(size_t)(k0 + i) * D_MODEL + n0 + tx]);
        __syncthreads();
        #pragma unroll
        for (int i = ty; i < 32; i += 8) o[(size_t)(n0 + i) * D_MODEL + k0 + tx] = t[tx][i];
    } else {
        int tid = ty * 32 + tx;
        size_t base = ((size_t)(blockIdx.y * 32 + blockIdx.x) * 256 + tid) * 16;
        #pragma unroll
        for (int c = 0; c < 4; ++c) {
            float4 v = *(const float4*)&X[base + c * 4];
            ushort4 o;
            o.x = f2u(v.x); o.y = f2u(v.y); o.z = f2u(v.z); o.w = f2u(v.w);
            *(ushort4*)&Xb[base + c * 4] = o;
        }
    }
}

// ---------------------------------------------------------------------------
// Fused QKV + V^T GEMM, 768 blocks (1D). 128x128 tile, BK=64, global_load_lds.
// ---------------------------------------------------------------------------
__launch_bounds__(256, 3)
__global__ void gemm_qkvt(const u16* __restrict__ xb, const u16* __restrict__ Wt,
                          const float* __restrict__ bq, const float* __restrict__ bk,
                          const float* __restrict__ bv, u16* __restrict__ QKw,
                          u16* __restrict__ Vtw) {
    constexpr int BK = 64;
    __shared__ __attribute__((aligned(16))) u16 As[128 * BK];
    __shared__ __attribute__((aligned(16))) u16 Bs[128 * BK];

    const int tid = threadIdx.x;
    const int w = tid >> 6;
    const int lane = tid & 63;
    const int lrow = lane & 15, lquad = lane >> 4;
    const size_t WSZ = (size_t)D_MODEL * D_MODEL;

    const int bid = blockIdx.x;
    const bool vt = bid >= 512;
    const int z = vt ? 2 : (bid >> 8);
    const int t = vt ? (bid - 512) : (bid & 255);
    const int n0 = vt ? (t & 31) * 128 : (t & 7) * 128;
    const int m0 = vt ? (t >> 5) * 128 : (t >> 3) * 128;
    const u16* Ap = vt ? (Wt + 2 * WSZ) : xb;
    const u16* Bp = vt ? xb : (Wt + (size_t)z * WSZ);
    const float* bias = vt ? bv : (z ? bk : bq);

    frag_cd acc[4][4];
    #pragma unroll
    for (int i = 0; i < 4; i++)
        #pragma unroll
        for (int j = 0; j < 4; j++) acc[i][j] = (frag_cd){0.f, 0.f, 0.f, 0.f};

    const int wm = (w >> 1) * 64, wn = (w & 1) * 64;

    for (int k0 = 0; k0 < D_MODEL; k0 += BK) {
        __syncthreads();
        #pragma unroll
        for (int it = 0; it < 4; ++it) {
            int c = it * 256 + tid;
            int r = c >> 3, c8 = c & 7;
            const u16* ga = Ap + (size_t)(m0 + r) * D_MODEL + k0 + c8 * 8;
            char* la = (char*)As + (it * 256 + w * 64) * 16;
            __builtin_amdgcn_global_load_lds((const __attribute__((address_space(1))) void*)ga,
                                             (__attribute__((address_space(3))) void*)la, 16, 0, 0);
            const u16* gb = Bp + (size_t)(n0 + r) * D_MODEL + k0 + c8 * 8;
            char* lb = (char*)Bs + (it * 256 + w * 64) * 16;
            __builtin_amdgcn_global_load_lds((const __attribute__((address_space(1))) void*)gb,
                                             (__attribute__((address_space(3))) void*)lb, 16, 0, 0);
        }
        __syncthreads();

        #pragma unroll
        for (int kc = 0; kc < 2; ++kc) {
            frag_ab av[4], bvv[4];
            #pragma unroll
            for (int i = 0; i < 4; i++)
                av[i] = *(const frag_ab*)&As[(wm + i * 16 + lrow) * BK + kc * 32 + lquad * 8];
            #pragma unroll
            for (int j = 0; j < 4; j++)
                bvv[j] = *(const frag_ab*)&Bs[(wn + j * 16 + lrow) * BK + kc * 32 + lquad * 8];
            #pragma unroll
            for (int i = 0; i < 4; i++)
                #pragma unroll
                for (int j = 0; j < 4; j++)
                    acc[i][j] = __builtin_amdgcn_mfma_f32_16x16x32_bf16(av[i], bvv[j], acc[i][j], 0, 0, 0);
        }
    }

    const float scale = (!vt && z == 0) ? QSCALE : 1.0f;
    #pragma unroll
    for (int j = 0; j < 4; j++) {
        int gn = n0 + wn + j * 16 + lrow;
        #pragma unroll
        for (int i = 0; i < 4; i++) {
            #pragma unroll
            for (int rr = 0; rr < 4; ++rr) {
                int gm = m0 + wm + i * 16 + lquad * 4 + rr;
                if (!vt) {
                    float v = (acc[i][j][rr] + bias[gn]) * scale;
                    u16* oz = QKw + (size_t)z * ((size_t)MTOT * D_MODEL);
                    int b = gm >> 11, s = gm & (SEQ - 1);
                    int h = gn >> 6, d = gn & (HDIM - 1);
                    oz[(((size_t)(b * NHEAD + h)) * SEQ + s) * HDIM + d] = f2u(v);
                } else {
                    float v = acc[i][j][rr] + bias[gm];
                    int h = gm >> 6, d = gm & (HDIM - 1);
                    int b = gn >> 11, s = gn & (SEQ - 1);
                    Vtw[(((size_t)(b * NHEAD + h)) * HDIM + d) * SEQ + s] = f2u(v);
                }
            }
        }
    }
}

// ---------------------------------------------------------------------------
// Out projection: 64x128 tile (512 blocks), fp32 store.
// ---------------------------------------------------------------------------
__launch_bounds__(256, 2)
__global__ void gemm_out(const u16* __restrict__ A, const u16* __restrict__ Wt,
                         const float* __restrict__ bias, float* __restrict__ out) {
    constexpr int BK = 64;
    __shared__ __attribute__((aligned(16))) u16 As[64 * BK];
    __shared__ __attribute__((aligned(16))) u16 Bs[128 * BK];

    const int tid = threadIdx.x;
    const int w = tid >> 6;
    const int lane = tid & 63;
    const int lrow = lane & 15, lquad = lane >> 4;
    const int m0 = blockIdx.y * 64, n0 = blockIdx.x * 128;

    frag_cd acc[2][4];
    #pragma unroll
    for (int i = 0; i < 2; i++)
        #pragma unroll
        for (int j = 0; j < 4; j++) acc[i][j] = (frag_cd){0.f, 0.f, 0.f, 0.f};

    const int wm = (w >> 1) * 32, wn = (w & 1) * 64;

    for (int k0 = 0; k0 < D_MODEL; k0 += BK) {
        __syncthreads();
        #pragma unroll
        for (int it = 0; it < 2; ++it) {
            int c = it * 256 + tid;
            int r = c >> 3, c8 = c & 7;
            const u16* ga = A + (size_t)(m0 + r) * D_MODEL + k0 + c8 * 8;
            char* la = (char*)As + (it * 256 + w * 64) * 16;
            __builtin_amdgcn_global_load_lds((const __attribute__((address_space(1))) void*)ga,
                                             (__attribute__((address_space(3))) void*)la, 16, 0, 0);
        }
        #pragma unroll
        for (int it = 0; it < 4; ++it) {
            int c = it * 256 + tid;
            int r = c >> 3, c8 = c & 7;
            const u16* gb = Wt + (size_t)(n0 + r) * D_MODEL + k0 + c8 * 8;
            char* lb = (char*)Bs + (it * 256 + w * 64) * 16;
            __builtin_amdgcn_global_load_lds((const __attribute__((address_space(1))) void*)gb,
                                             (__attribute__((address_space(3))) void*)lb, 16, 0, 0);
        }
        __syncthreads();

        #pragma unroll
        for (int kc = 0; kc < 2; ++kc) {
            frag_ab av[2], bvv[4];
            #pragma unroll
            for (int i = 0; i < 2; i++)
                av[i] = *(const frag_ab*)&As[(wm + i * 16 + lrow) * BK + kc * 32 + lquad * 8];
            #pragma unroll
            for (int j = 0; j < 4; j++)
                bvv[j] = *(const frag_ab*)&Bs[(wn + j * 16 + lrow) * BK + kc * 32 + lquad * 8];
            #pragma unroll
            for (int i = 0; i < 2; i++)
                #pragma unroll
                for (int j = 0; j < 4; j++)
                    acc[i][j] = __builtin_amdgcn_mfma_f32_16x16x32_bf16(av[i], bvv[j], acc[i][j], 0, 0, 0);
        }
    }

    #pragma unroll
    for (int j = 0; j < 4; j++) {
        int gn = n0 + wn + j * 16 + lrow;
        float bvf = bias[gn];
        #pragma unroll
        for (int i = 0; i < 2; i++)
            #pragma unroll
            for (int rr = 0; rr < 4; ++rr) {
                int gm = m0 + wm + i * 16 + lquad * 4 + rr;
                out[(size_t)gm * D_MODEL + gn] = acc[i][j][rr] + bvf;
            }
    }
}

// ---------------------------------------------------------------------------
// Attention (transposed, register-resident P), 32 q per wave.
// Grid (16,32), 256 thr (4 waves x 32 q = 128 q/block), 2 blocks/CU.
// Per 128-key tile: S^T = K.Q^T (each Ks b128 read feeds 2 MFMAs, one per
// q-set); p = exp2 in regs; packed P feeds PV (each Vs b64 read feeds 2
// mfma_16x16x16). Per-q LDS read traffic is half of R9's.
// LDS: Ks 128x72 + Vs 64x128 (XOR-swizzled) = 34 KB.
// ---------------------------------------------------------------------------
__launch_bounds__(256, 2)
__global__ void attn_kernel(const u16* __restrict__ Q, const u16* __restrict__ K,
                            const u16* __restrict__ Vt, u16* __restrict__ O) {
    constexpr int SKK = 72;   // K row stride (64 d + pad)
    __shared__ __attribute__((aligned(16))) u16 Ks[128 * SKK];
    __shared__ __attribute__((aligned(16))) u16 Vs[64 * 128];  // swizzled

    const int tid = threadIdx.x;
    const int w = tid >> 6;           // 4 waves
    const int lane = tid & 63;
    const int lrow = lane & 15, lquad = lane >> 4;
    const int bh = blockIdx.y;
    const int q0 = blockIdx.x * 128;
    const size_t base = (size_t)bh * SEQ * HDIM;
    const u16* Qg = Q + base;
    const u16* Kg = K + base;
    const u16* Vg = Vt + base;  // [d][s]

    // Q as B-operand: set s handles q = q0 + w*32 + s*16 + lrow
    frag_ab qf[2][2];
    #pragma unroll
    for (int s = 0; s < 2; ++s)
        #pragma unroll
        for (int kc = 0; kc < 2; ++kc)
            qf[s][kc] = *(const frag_ab*)&Qg[(size_t)(q0 + w * 32 + s * 16 + lrow) * HDIM + kc * 32 + lquad * 8];

    frag_cd accOT[2][4];   // O^T per set: lane q = lrow, d = df*16 + lquad*4 + i
    #pragma unroll
    for (int s = 0; s < 2; ++s)
        #pragma unroll
        for (int df = 0; df < 4; df++) accOT[s][df] = (frag_cd){0.f, 0.f, 0.f, 0.f};
    float lacc[2] = {0.f, 0.f};

    for (int kt = 0; kt < SEQ / 128; ++kt) {
        __syncthreads();
        #pragma unroll
        for (int it = 0; it < 4; ++it) {
            int c = it * 256 + tid;
            int rk = c >> 3, ck = (c & 7) * 8;
            *(uint4*)&Ks[rk * SKK + ck] = *(const uint4*)&Kg[(size_t)(kt * 128 + rk) * HDIM + ck];
            int rv = c >> 4, gv = c & 15;   // row d, 16B chunk index
            *(uint4*)&Vs[rv * 128 + ((gv ^ (rv & 7)) << 3)] =
                *(const uint4*)&Vg[(size_t)rv * SEQ + kt * 128 + gv * 8];
        }
        __syncthreads();

        // S^T[key][q]: A = K (m=key), B = Q-set. kf loaded once, used twice.
        frag_cd sc[2][8];
        #pragma unroll
        for (int s = 0; s < 2; ++s)
            #pragma unroll
            for (int mf = 0; mf < 8; mf++) sc[s][mf] = (frag_cd){0.f, 0.f, 0.f, 0.f};
        #pragma unroll
        for (int kc = 0; kc < 2; ++kc)
            #pragma unroll
            for (int mf = 0; mf < 8; mf++) {
                frag_ab kf = *(const frag_ab*)&Ks[(mf * 16 + lrow) * SKK + kc * 32 + lquad * 8];
                #pragma unroll
                for (int s = 0; s < 2; ++s)
                    sc[s][mf] = __builtin_amdgcn_mfma_f32_16x16x32_bf16(kf, qf[s][kc], sc[s][mf], 0, 0, 0);
            }

        // p = 2^s in-register; per-lane rowsum partials; pack via v_cvt_pk_bf16_f32
        frag_s4 pk[2][8];
        #pragma unroll
        for (int s = 0; s < 2; ++s)
            #pragma unroll
            for (int mf = 0; mf < 8; mf++) {
                float e0 = exp2f(sc[s][mf][0]), e1 = exp2f(sc[s][mf][1]);
                float e2 = exp2f(sc[s][mf][2]), e3 = exp2f(sc[s][mf][3]);
                lacc[s] += (e0 + e1) + (e2 + e3);
                union { frag_s4 v; unsigned int u[2]; } pu;
                pu.u[0] = pkrn(e0, e1);
                pu.u[1] = pkrn(e2, e3);
                pk[s][mf] = pu.v;
            }

        // O^T += V^T . P^T : vf loaded once per (mf,df), used for both sets
        #pragma unroll
        for (int mf = 0; mf < 8; mf++)
            #pragma unroll
            for (int df = 0; df < 4; df++) {
                int dr = df * 16 + lrow;
                int g = 2 * mf + (lquad >> 1);
                frag_s4 vf = *(const frag_s4*)&Vs[dr * 128 + ((g ^ (dr & 7)) << 3) + (lquad & 1) * 4];
                #pragma unroll
                for (int s = 0; s < 2; ++s)
                    accOT[s][df] = __builtin_amdgcn_mfma_f32_16x16x16bf16_1k(vf, pk[s][mf], accOT[s][df], 0, 0, 0);
            }
    }

    // reduce rowsums across the 4 quads holding each q
    #pragma unroll
    for (int s = 0; s < 2; ++s) {
        lacc[s] += __shfl_xor(lacc[s], 16);
        lacc[s] += __shfl_xor(lacc[s], 32);
    }

    // epilogue: lane owns one q per set; packed cvt + b64 stores
    const int b = bh >> 4, h = bh & (NHEAD - 1);
    #pragma unroll
    for (int s = 0; s < 2; ++s) {
        const int sq = q0 + w * 32 + s * 16 + lrow;
        const float inv = 1.0f / lacc[s];
        u16* orow = O + ((size_t)(b * SEQ + sq)) * D_MODEL + h * HDIM;
        #pragma unroll
        for (int df = 0; df < 4; df++) {
            union { unsigned int u[2]; ushort4 s4; } o;
            o.u[0] = pkrn(accOT[s][df][0] * inv, accOT[s][df][1] * inv);
            o.u[1] = pkrn(accOT[s][df][2] * inv, accOT[s][df][3] * inv);
            *(ushort4*)&orow[df * 16 + lquad * 4] = o.s4;
        }
    }
}

// ---------------------------------------------------------------------------
// Workspace (u16 elems): xb [0,4M) | Wt 4 slabs [4M,8M) | Q,K [8M,16M)
//                        Vt [16M,20M) | attn-out [20M,24M)   = 48 MB
// ---------------------------------------------------------------------------
extern "C" void kernel_launch(void* const* d_in, const int* in_sizes, int n_in,
                              void* d_out, int out_size, void* d_ws, size_t ws_size,
                              hipStream_t stream) {
    const float* x  = (const float*)d_in[0];
    const float* Wq = (const float*)d_in[1];
    const float* bq = (const float*)d_in[2];
    const float* Wk = (const float*)d_in[3];
    const float* bk = (const float*)d_in[4];
    const float* Wv = (const float*)d_in[5];
    const float* bv = (const float*)d_in[6];
    const float* Wo = (const float*)d_in[7];
    const float* bo = (const float*)d_in[8];

    u16* ws = (u16*)d_ws;
    const size_t WSZ = (size_t)D_MODEL * D_MODEL;    // 1M elems
    const size_t TSZ = (size_t)MTOT * D_MODEL;       // 4M elems
    u16* xb  = ws;
    u16* Wt  = ws + 4 * WSZ;
    u16* QKw = ws + 8 * WSZ;        // Q slab 0, K slab 1
    u16* Vtw = QKw + 2 * TSZ;
    u16* Aw  = Vtw + TSZ;

    prep<<<dim3(32, 32, 5), dim3(32, 8), 0, stream>>>(Wq, Wk, Wv, Wo, x, Wt, xb);
    gemm_qkvt<<<dim3(768), 256, 0, stream>>>(xb, Wt, bq, bk, bv, QKw, Vtw);
    attn_kernel<<<dim3(16, 32), 256, 0, stream>>>(QKw, QKw + TSZ, Vtw, Aw);
    gemm_out<<<dim3(8, 64), 256, 0, stream>>>(Aw, Wt + 3 * WSZ, bo, (float*)d_out);
}

// Round 11
// 222.220 us; speedup vs baseline: 1.0314x; 1.0314x over previous
//
#include <hip/hip_runtime.h>
#include <hip/hip_bf16.h>

// MultiBertAttention fp32 I/O, bf16 MFMA internals.
// R11: revert R10 (2 waves/SIMD was latency-bound; LDS-traffic halving didn't pay).
//      attn = R9 core (16q/wave, 512 thr, 4 waves/SIMD) + XCD-aware grid
//      (x=bh, y=q-tile: same-head blocks -> same XCD -> K/V L2-resident).
//      gemm_qkvt back to __launch_bounds__(256,2) (R6->R7 differencing showed
//      (256,3) cost ~6us via VGPR squeeze).

typedef unsigned short u16;

#define D_MODEL 1024
#define NHEAD 16
#define HDIM 64
#define BATCH 2
#define SEQ 2048
#define MTOT (BATCH * SEQ)  // 4096

#define QSCALE 0.18033688011112042f  // (1/8) * log2(e)

using frag_ab = __attribute__((ext_vector_type(8))) short;  // 8 bf16 (16x16x32 A/B)
using frag_s4 = __attribute__((ext_vector_type(4))) short;  // 4 bf16 (16x16x16 A/B)
using frag_cd = __attribute__((ext_vector_type(4))) float;  // 4 fp32

__device__ __forceinline__ u16 f2u(float f) {  // RNE fp32->bf16
    union { float f; unsigned int i; } x;
    x.f = f;
    unsigned int r = x.i + 0x7fffu + ((x.i >> 16) & 1u);
    return (u16)(r >> 16);
}
__device__ __forceinline__ unsigned int pkrn(float a, float b) {  // v_cvt_pk_bf16_f32
    union { __hip_bfloat162 h; unsigned int u; } c;
    c.h = __float22bfloat162_rn(float2{a, b});
    return c.u;
}

// ---------------------------------------------------------------------------
// prep: z<4 -> Wt[z][n][k] = bf16(W_z[k][n]); z==4 -> xb = bf16(x).
// ---------------------------------------------------------------------------
__global__ void prep(const float* __restrict__ W0, const float* __restrict__ W1,
                     const float* __restrict__ W2, const float* __restrict__ W3,
                     const float* __restrict__ X, u16* __restrict__ Wt,
                     u16* __restrict__ Xb) {
    const int z = blockIdx.z;
    const int tx = threadIdx.x, ty = threadIdx.y;
    if (z < 4) {
        __shared__ u16 t[32][33];
        const float* W = (z == 0) ? W0 : (z == 1) ? W1 : (z == 2) ? W2 : W3;
        u16* o = Wt + (size_t)z * D_MODEL * D_MODEL;
        int n0 = blockIdx.x * 32, k0 = blockIdx.y * 32;
        #pragma unroll
        for (int i = ty; i < 32; i += 8) t[i][tx] = f2u(W[(size_t)(k0 + i) * D_MODEL + n0 + tx]);
        __syncthreads();
        #pragma unroll
        for (int i = ty; i < 32; i += 8) o[(size_t)(n0 + i) * D_MODEL + k0 + tx] = t[tx][i];
    } else {
        int tid = ty * 32 + tx;
        size_t base = ((size_t)(blockIdx.y * 32 + blockIdx.x) * 256 + tid) * 16;
        #pragma unroll
        for (int c = 0; c < 4; ++c) {
            float4 v = *(const float4*)&X[base + c * 4];
            ushort4 o;
            o.x = f2u(v.x); o.y = f2u(v.y); o.z = f2u(v.z); o.w = f2u(v.w);
            *(ushort4*)&Xb[base + c * 4] = o;
        }
    }
}

// ---------------------------------------------------------------------------
// Fused QKV + V^T GEMM, 768 blocks (1D). 128x128 tile, BK=64, global_load_lds.
// ---------------------------------------------------------------------------
__launch_bounds__(256, 2)
__global__ void gemm_qkvt(const u16* __restrict__ xb, const u16* __restrict__ Wt,
                          const float* __restrict__ bq, const float* __restrict__ bk,
                          const float* __restrict__ bv, u16* __restrict__ QKw,
                          u16* __restrict__ Vtw) {
    constexpr int BK = 64;
    __shared__ __attribute__((aligned(16))) u16 As[128 * BK];
    __shared__ __attribute__((aligned(16))) u16 Bs[128 * BK];

    const int tid = threadIdx.x;
    const int w = tid >> 6;
    const int lane = tid & 63;
    const int lrow = lane & 15, lquad = lane >> 4;
    const size_t WSZ = (size_t)D_MODEL * D_MODEL;

    const int bid = blockIdx.x;
    const bool vt = bid >= 512;
    const int z = vt ? 2 : (bid >> 8);
    const int t = vt ? (bid - 512) : (bid & 255);
    const int n0 = vt ? (t & 31) * 128 : (t & 7) * 128;
    const int m0 = vt ? (t >> 5) * 128 : (t >> 3) * 128;
    const u16* Ap = vt ? (Wt + 2 * WSZ) : xb;
    const u16* Bp = vt ? xb : (Wt + (size_t)z * WSZ);
    const float* bias = vt ? bv : (z ? bk : bq);

    frag_cd acc[4][4];
    #pragma unroll
    for (int i = 0; i < 4; i++)
        #pragma unroll
        for (int j = 0; j < 4; j++) acc[i][j] = (frag_cd){0.f, 0.f, 0.f, 0.f};

    const int wm = (w >> 1) * 64, wn = (w & 1) * 64;

    for (int k0 = 0; k0 < D_MODEL; k0 += BK) {
        __syncthreads();
        #pragma unroll
        for (int it = 0; it < 4; ++it) {
            int c = it * 256 + tid;
            int r = c >> 3, c8 = c & 7;
            const u16* ga = Ap + (size_t)(m0 + r) * D_MODEL + k0 + c8 * 8;
            char* la = (char*)As + (it * 256 + w * 64) * 16;
            __builtin_amdgcn_global_load_lds((const __attribute__((address_space(1))) void*)ga,
                                             (__attribute__((address_space(3))) void*)la, 16, 0, 0);
            const u16* gb = Bp + (size_t)(n0 + r) * D_MODEL + k0 + c8 * 8;
            char* lb = (char*)Bs + (it * 256 + w * 64) * 16;
            __builtin_amdgcn_global_load_lds((const __attribute__((address_space(1))) void*)gb,
                                             (__attribute__((address_space(3))) void*)lb, 16, 0, 0);
        }
        __syncthreads();

        #pragma unroll
        for (int kc = 0; kc < 2; ++kc) {
            frag_ab av[4], bvv[4];
            #pragma unroll
            for (int i = 0; i < 4; i++)
                av[i] = *(const frag_ab*)&As[(wm + i * 16 + lrow) * BK + kc * 32 + lquad * 8];
            #pragma unroll
            for (int j = 0; j < 4; j++)
                bvv[j] = *(const frag_ab*)&Bs[(wn + j * 16 + lrow) * BK + kc * 32 + lquad * 8];
            #pragma unroll
            for (int i = 0; i < 4; i++)
                #pragma unroll
                for (int j = 0; j < 4; j++)
                    acc[i][j] = __builtin_amdgcn_mfma_f32_16x16x32_bf16(av[i], bvv[j], acc[i][j], 0, 0, 0);
        }
    }

    const float scale = (!vt && z == 0) ? QSCALE : 1.0f;
    #pragma unroll
    for (int j = 0; j < 4; j++) {
        int gn = n0 + wn + j * 16 + lrow;
        #pragma unroll
        for (int i = 0; i < 4; i++) {
            #pragma unroll
            for (int rr = 0; rr < 4; ++rr) {
                int gm = m0 + wm + i * 16 + lquad * 4 + rr;
                if (!vt) {
                    float v = (acc[i][j][rr] + bias[gn]) * scale;
                    u16* oz = QKw + (size_t)z * ((size_t)MTOT * D_MODEL);
                    int b = gm >> 11, s = gm & (SEQ - 1);
                    int h = gn >> 6, d = gn & (HDIM - 1);
                    oz[(((size_t)(b * NHEAD + h)) * SEQ + s) * HDIM + d] = f2u(v);
                } else {
                    float v = acc[i][j][rr] + bias[gm];
                    int h = gm >> 6, d = gm & (HDIM - 1);
                    int b = gn >> 11, s = gn & (SEQ - 1);
                    Vtw[(((size_t)(b * NHEAD + h)) * HDIM + d) * SEQ + s] = f2u(v);
                }
            }
        }
    }
}

// ---------------------------------------------------------------------------
// Out projection: 64x128 tile (512 blocks), fp32 store.
// ---------------------------------------------------------------------------
__launch_bounds__(256, 2)
__global__ void gemm_out(const u16* __restrict__ A, const u16* __restrict__ Wt,
                         const float* __restrict__ bias, float* __restrict__ out) {
    constexpr int BK = 64;
    __shared__ __attribute__((aligned(16))) u16 As[64 * BK];
    __shared__ __attribute__((aligned(16))) u16 Bs[128 * BK];

    const int tid = threadIdx.x;
    const int w = tid >> 6;
    const int lane = tid & 63;
    const int lrow = lane & 15, lquad = lane >> 4;
    const int m0 = blockIdx.y * 64, n0 = blockIdx.x * 128;

    frag_cd acc[2][4];
    #pragma unroll
    for (int i = 0; i < 2; i++)
        #pragma unroll
        for (int j = 0; j < 4; j++) acc[i][j] = (frag_cd){0.f, 0.f, 0.f, 0.f};

    const int wm = (w >> 1) * 32, wn = (w & 1) * 64;

    for (int k0 = 0; k0 < D_MODEL; k0 += BK) {
        __syncthreads();
        #pragma unroll
        for (int it = 0; it < 2; ++it) {
            int c = it * 256 + tid;
            int r = c >> 3, c8 = c & 7;
            const u16* ga = A + (size_t)(m0 + r) * D_MODEL + k0 + c8 * 8;
            char* la = (char*)As + (it * 256 + w * 64) * 16;
            __builtin_amdgcn_global_load_lds((const __attribute__((address_space(1))) void*)ga,
                                             (__attribute__((address_space(3))) void*)la, 16, 0, 0);
        }
        #pragma unroll
        for (int it = 0; it < 4; ++it) {
            int c = it * 256 + tid;
            int r = c >> 3, c8 = c & 7;
            const u16* gb = Wt + (size_t)(n0 + r) * D_MODEL + k0 + c8 * 8;
            char* lb = (char*)Bs + (it * 256 + w * 64) * 16;
            __builtin_amdgcn_global_load_lds((const __attribute__((address_space(1))) void*)gb,
                                             (__attribute__((address_space(3))) void*)lb, 16, 0, 0);
        }
        __syncthreads();

        #pragma unroll
        for (int kc = 0; kc < 2; ++kc) {
            frag_ab av[2], bvv[4];
            #pragma unroll
            for (int i = 0; i < 2; i++)
                av[i] = *(const frag_ab*)&As[(wm + i * 16 + lrow) * BK + kc * 32 + lquad * 8];
            #pragma unroll
            for (int j = 0; j < 4; j++)
                bvv[j] = *(const frag_ab*)&Bs[(wn + j * 16 + lrow) * BK + kc * 32 + lquad * 8];
            #pragma unroll
            for (int i = 0; i < 2; i++)
                #pragma unroll
                for (int j = 0; j < 4; j++)
                    acc[i][j] = __builtin_amdgcn_mfma_f32_16x16x32_bf16(av[i], bvv[j], acc[i][j], 0, 0, 0);
        }
    }

    #pragma unroll
    for (int j = 0; j < 4; j++) {
        int gn = n0 + wn + j * 16 + lrow;
        float bvf = bias[gn];
        #pragma unroll
        for (int i = 0; i < 2; i++)
            #pragma unroll
            for (int rr = 0; rr < 4; ++rr) {
                int gm = m0 + wm + i * 16 + lquad * 4 + rr;
                out[(size_t)gm * D_MODEL + gn] = acc[i][j][rr] + bvf;
            }
    }
}

// ---------------------------------------------------------------------------
// Attention (transposed, register-resident P) - R9 core, XCD-aware grid.
// Grid (32, 16): x = bh (blocks sharing a head's K/V get consecutive-mod-8
// ids -> same XCD -> K/V L2-resident), y = q-tile. 512 thr (8 waves x 16 q).
// S^T = K.Q^T via mfma_16x16x32; p = exp2 in regs; packed P (v_cvt_pk_bf16_f32)
// feeds PV (O^T = V^T.P^T) via mfma_16x16x16 B-operand. Vs XOR-swizzled.
// LDS: Ks 128x72 + Vs 64x128 = 34 KB.
// ---------------------------------------------------------------------------
__launch_bounds__(512, 4)
__global__ void attn_kernel(const u16* __restrict__ Q, const u16* __restrict__ K,
                            const u16* __restrict__ Vt, u16* __restrict__ O) {
    constexpr int SKK = 72;   // K row stride (64 d + pad)
    __shared__ __attribute__((aligned(16))) u16 Ks[128 * SKK];
    __shared__ __attribute__((aligned(16))) u16 Vs[64 * 128];  // swizzled

    const int tid = threadIdx.x;
    const int w = tid >> 6;           // 8 waves
    const int lane = tid & 63;
    const int lrow = lane & 15, lquad = lane >> 4;
    const int bh = blockIdx.x;        // XCD swizzle: same bh -> same XCD
    const int q0 = blockIdx.y * 128;
    const size_t base = (size_t)bh * SEQ * HDIM;
    const u16* Qg = Q + base;
    const u16* Kg = K + base;
    const u16* Vg = Vt + base;  // [d][s]

    // Q as B-operand of 16x16x32: lane holds q = lrow, d = kc*32 + lquad*8 + j
    frag_ab qf[2];
    #pragma unroll
    for (int kc = 0; kc < 2; ++kc)
        qf[kc] = *(const frag_ab*)&Qg[(size_t)(q0 + w * 16 + lrow) * HDIM + kc * 32 + lquad * 8];

    frag_cd accOT[4];   // O^T: lane q = lrow, d = df*16 + lquad*4 + i
    #pragma unroll
    for (int df = 0; df < 4; df++) accOT[df] = (frag_cd){0.f, 0.f, 0.f, 0.f};
    float lacc = 0.f;   // per-lane softmax denom partial (reduced in epilogue)

    for (int kt = 0; kt < SEQ / 128; ++kt) {
        __syncthreads();
        #pragma unroll
        for (int it = 0; it < 2; ++it) {
            int c = it * 512 + tid;
            int rk = c >> 3, ck = (c & 7) * 8;
            *(uint4*)&Ks[rk * SKK + ck] = *(const uint4*)&Kg[(size_t)(kt * 128 + rk) * HDIM + ck];
            int rv = c >> 4, gv = c & 15;   // row d, 16B chunk index
            *(uint4*)&Vs[rv * 128 + ((gv ^ (rv & 7)) << 3)] =
                *(const uint4*)&Vg[(size_t)rv * SEQ + kt * 128 + gv * 8];
        }
        __syncthreads();

        // S^T[key][q]: A = K (m=key), B = Q. C-layout: col=q=lrow, row=key=mf*16+lquad*4+i
        frag_cd sc[8];
        #pragma unroll
        for (int mf = 0; mf < 8; mf++) sc[mf] = (frag_cd){0.f, 0.f, 0.f, 0.f};
        #pragma unroll
        for (int kc = 0; kc < 2; ++kc)
            #pragma unroll
            for (int mf = 0; mf < 8; mf++) {
                frag_ab kf = *(const frag_ab*)&Ks[(mf * 16 + lrow) * SKK + kc * 32 + lquad * 8];
                sc[mf] = __builtin_amdgcn_mfma_f32_16x16x32_bf16(kf, qf[kc], sc[mf], 0, 0, 0);
            }

        // p = 2^s in-register; per-lane rowsum partial; pack via v_cvt_pk_bf16_f32
        frag_s4 pk[8];
        #pragma unroll
        for (int mf = 0; mf < 8; mf++) {
            float e0 = exp2f(sc[mf][0]), e1 = exp2f(sc[mf][1]);
            float e2 = exp2f(sc[mf][2]), e3 = exp2f(sc[mf][3]);
            lacc += (e0 + e1) + (e2 + e3);
            union { frag_s4 s; unsigned int u[2]; } pu;
            pu.u[0] = pkrn(e0, e1);
            pu.u[1] = pkrn(e2, e3);
            pk[mf] = pu.s;
        }

        // O^T += V^T . P^T : A = V^T (m=d, k=key, swizzled b64 from Vs), B = pk
        #pragma unroll
        for (int mf = 0; mf < 8; mf++)
            #pragma unroll
            for (int df = 0; df < 4; df++) {
                int dr = df * 16 + lrow;
                int g = 2 * mf + (lquad >> 1);
                frag_s4 vf = *(const frag_s4*)&Vs[dr * 128 + ((g ^ (dr & 7)) << 3) + (lquad & 1) * 4];
                accOT[df] = __builtin_amdgcn_mfma_f32_16x16x16bf16_1k(vf, pk[mf], accOT[df], 0, 0, 0);
            }
    }

    // reduce rowsum across the 4 quads holding this q
    lacc += __shfl_xor(lacc, 16);
    lacc += __shfl_xor(lacc, 32);

    // epilogue: lane owns one q -> single reciprocal; packed cvt + b64 stores
    const int b = bh >> 4, h = bh & (NHEAD - 1);
    const int s = q0 + w * 16 + lrow;
    const float inv = 1.0f / lacc;
    u16* orow = O + ((size_t)(b * SEQ + s)) * D_MODEL + h * HDIM;
    #pragma unroll
    for (int df = 0; df < 4; df++) {
        union { unsigned int u[2]; ushort4 s4; } o;
        o.u[0] = pkrn(accOT[df][0] * inv, accOT[df][1] * inv);
        o.u[1] = pkrn(accOT[df][2] * inv, accOT[df][3] * inv);
        *(ushort4*)&orow[df * 16 + lquad * 4] = o.s4;
    }
}

// ---------------------------------------------------------------------------
// Workspace (u16 elems): xb [0,4M) | Wt 4 slabs [4M,8M) | Q,K [8M,16M)
//                        Vt [16M,20M) | attn-out [20M,24M)   = 48 MB
// ---------------------------------------------------------------------------
extern "C" void kernel_launch(void* const* d_in, const int* in_sizes, int n_in,
                              void* d_out, int out_size, void* d_ws, size_t ws_size,
                              hipStream_t stream) {
    const float* x  = (const float*)d_in[0];
    const float* Wq = (const float*)d_in[1];
    const float* bq = (const float*)d_in[2];
    const float* Wk = (const float*)d_in[3];
    const float* bk = (const float*)d_in[4];
    const float* Wv = (const float*)d_in[5];
    const float* bv = (const float*)d_in[6];
    const float* Wo = (const float*)d_in[7];
    const float* bo = (const float*)d_in[8];

    u16* ws = (u16*)d_ws;
    const size_t WSZ = (size_t)D_MODEL * D_MODEL;    // 1M elems
    const size_t TSZ = (size_t)MTOT * D_MODEL;       // 4M elems
    u16* xb  = ws;
    u16* Wt  = ws + 4 * WSZ;
    u16* QKw = ws + 8 * WSZ;        // Q slab 0, K slab 1
    u16* Vtw = QKw + 2 * TSZ;
    u16* Aw  = Vtw + TSZ;

    prep<<<dim3(32, 32, 5), dim3(32, 8), 0, stream>>>(Wq, Wk, Wv, Wo, x, Wt, xb);
    gemm_qkvt<<<dim3(768), 256, 0, stream>>>(xb, Wt, bq, bk, bv, QKw, Vtw);
    attn_kernel<<<dim3(32, 16), 512, 0, stream>>>(QKw, QKw + TSZ, Vtw, Aw);
    gemm_out<<<dim3(8, 64), 256, 0, stream>>>(Aw, Wt + 3 * WSZ, bo, (float*)d_out);
}